// Round 1
// baseline (631.475 us; speedup 1.0000x reference)
//
#include <hip/hip_runtime.h>
#include <hip/hip_bf16.h>

#define S_LEN 4096
#define DMODEL 1024
#define NHEADS 16
#define HDIM 64

typedef __bf16 bf16_8 __attribute__((ext_vector_type(8)));
typedef float f32x4 __attribute__((ext_vector_type(4)));
typedef unsigned short u16;
typedef unsigned int u32;

__device__ __forceinline__ u16 f2bf(float f) {
    union { float f; u32 u; } v; v.f = f;
    u32 r = v.u + 0x7FFFu + ((v.u >> 16) & 1u);
    return (u16)(r >> 16);
}
__device__ __forceinline__ float bf2f(u16 h) {
    union { u32 u; float f; } v; v.u = ((u32)h) << 16;
    return v.f;
}

// ---------------- fp32 -> bf16 conversion ----------------
__global__ void cvt_kernel(const float* __restrict__ src, u16* __restrict__ dst, int n) {
    int i = (blockIdx.x * blockDim.x + threadIdx.x) * 4;
    int stride = gridDim.x * blockDim.x * 4;
    for (; i < n; i += stride) {
        float4 v = *reinterpret_cast<const float4*>(src + i);
        ushort4 o;
        o.x = f2bf(v.x); o.y = f2bf(v.y); o.z = f2bf(v.z); o.w = f2bf(v.w);
        *reinterpret_cast<ushort4*>(dst + i) = o;
    }
}

// ---------------- RoPE tables ----------------
__global__ void rope_table_kernel(float* __restrict__ cosT, float* __restrict__ sinT) {
    int idx = blockIdx.x * blockDim.x + threadIdx.x;
    if (idx >= S_LEN * 32) return;
    int s = idx >> 5, i = idx & 31;
    float inv = expf(-((float)(2 * i) / (float)HDIM) * logf(10000.0f));
    float fr = (float)s * inv;
    cosT[idx] = cosf(fr);
    sinT[idx] = sinf(fr);
}

// ---------------- RoPE apply (in-place on Q or K, (H,S,hd) bf16) ----------------
__global__ void rope_kernel(u16* __restrict__ Qb, u16* __restrict__ Kb,
                            const float* __restrict__ cosT, const float* __restrict__ sinT) {
    int idx = blockIdx.x * blockDim.x + threadIdx.x; // over NHEADS*S_LEN*32
    if (idx >= NHEADS * S_LEN * 32) return;
    u16* buf = blockIdx.y ? Kb : Qb;
    int i = idx & 31;
    int s = (idx >> 5) & (S_LEN - 1);
    int h = idx >> 17;
    size_t base = ((size_t)h * S_LEN + s) * HDIM;
    float c = cosT[(s << 5) + i], sn = sinT[(s << 5) + i];
    float x1 = bf2f(buf[base + i]);
    float x2 = bf2f(buf[base + i + 32]);
    buf[base + i] = f2bf(x1 * c - x2 * sn);
    buf[base + i + 32] = f2bf(x2 * c + x1 * sn);
}

// ---------------- GEMM: C = A(MxK) @ B(NxK)^T + bias ----------------
// MODE 0: three outputs (Q,K,V) selected by blockIdx.z, written bf16 as (H,S,hd)
// MODE 1: single output, fp32 row-major (S, D) to d_out
template<int MODE>
__global__ __launch_bounds__(256) void gemm_bt_kernel(
    const u16* __restrict__ A,
    const u16* __restrict__ B0, const u16* __restrict__ B1, const u16* __restrict__ B2,
    const float* __restrict__ bias0, const float* __restrict__ bias1, const float* __restrict__ bias2,
    u16* __restrict__ dst0, u16* __restrict__ dst1, u16* __restrict__ dst2,
    float* __restrict__ outF)
{
    const int bm = blockIdx.y * 64;
    const int bn = blockIdx.x * 64;
    const u16* B = B0; const float* bias = bias0; u16* dst = dst0;
    if (MODE == 0) {
        if (blockIdx.z == 1)      { B = B1; bias = bias1; dst = dst1; }
        else if (blockIdx.z == 2) { B = B2; bias = bias2; dst = dst2; }
    }
    __shared__ __align__(16) u16 As[64][40];
    __shared__ __align__(16) u16 Bs[64][40];
    const int tid = threadIdx.x;
    const int lane = tid & 63;
    const int wid = tid >> 6;
    const int wm = (wid >> 1) * 32;
    const int wn = (wid & 1) * 32;
    const int lrow = tid >> 2;        // 0..63
    const int lcol = (tid & 3) << 3;  // 0,8,16,24
    f32x4 acc[2][2] = {};
    for (int k0 = 0; k0 < DMODEL; k0 += 32) {
        uint4 av = *reinterpret_cast<const uint4*>(A + (size_t)(bm + lrow) * DMODEL + k0 + lcol);
        uint4 bv = *reinterpret_cast<const uint4*>(B + (size_t)(bn + lrow) * DMODEL + k0 + lcol);
        __syncthreads();
        *reinterpret_cast<uint4*>(&As[lrow][lcol]) = av;
        *reinterpret_cast<uint4*>(&Bs[lrow][lcol]) = bv;
        __syncthreads();
        bf16_8 a0 = *reinterpret_cast<const bf16_8*>(&As[wm + (lane & 15)][(lane >> 4) * 8]);
        bf16_8 a1 = *reinterpret_cast<const bf16_8*>(&As[wm + 16 + (lane & 15)][(lane >> 4) * 8]);
        bf16_8 b0 = *reinterpret_cast<const bf16_8*>(&Bs[wn + (lane & 15)][(lane >> 4) * 8]);
        bf16_8 b1 = *reinterpret_cast<const bf16_8*>(&Bs[wn + 16 + (lane & 15)][(lane >> 4) * 8]);
        acc[0][0] = __builtin_amdgcn_mfma_f32_16x16x32_bf16(a0, b0, acc[0][0], 0, 0, 0);
        acc[0][1] = __builtin_amdgcn_mfma_f32_16x16x32_bf16(a0, b1, acc[0][1], 0, 0, 0);
        acc[1][0] = __builtin_amdgcn_mfma_f32_16x16x32_bf16(a1, b0, acc[1][0], 0, 0, 0);
        acc[1][1] = __builtin_amdgcn_mfma_f32_16x16x32_bf16(a1, b1, acc[1][1], 0, 0, 0);
    }
    #pragma unroll
    for (int mi = 0; mi < 2; mi++) {
        #pragma unroll
        for (int ni = 0; ni < 2; ni++) {
            int col = bn + wn + ni * 16 + (lane & 15);
            float bval = bias[col];
            #pragma unroll
            for (int r = 0; r < 4; r++) {
                int row = bm + wm + mi * 16 + (lane >> 4) * 4 + r;
                float val = acc[mi][ni][r] + bval;
                if (MODE == 0) {
                    int h = col >> 6, d = col & 63;
                    dst[((size_t)h * S_LEN + row) * HDIM + d] = f2bf(val);
                } else {
                    outF[(size_t)row * DMODEL + col] = val;
                }
            }
        }
    }
}

// ---------------- causal flash attention ----------------
// grid (S/64, H); block 256 = 4 waves, wave w handles q-rows [bx*64+16w, +16)
__global__ __launch_bounds__(256) void attn_kernel(
    const u16* __restrict__ Q, const u16* __restrict__ K, const u16* __restrict__ V,
    u16* __restrict__ AO)
{
    const int bx = blockIdx.x;
    const int h = blockIdx.y;
    const int tid = threadIdx.x;
    const int lane = tid & 63;
    const int wid = tid >> 6;
    const int q0 = bx * 64 + wid * 16;
    const u16* Qh = Q + (size_t)h * S_LEN * HDIM;
    const u16* Kh = K + (size_t)h * S_LEN * HDIM;
    const u16* Vh = V + (size_t)h * S_LEN * HDIM;

    __shared__ __align__(16) u16 Ks[32][72];
    __shared__ __align__(16) u16 Vs[32][72];
    __shared__ __align__(16) u16 Ps[4][16][40];

    bf16_8 qf[2];
    #pragma unroll
    for (int db = 0; db < 2; db++)
        qf[db] = *reinterpret_cast<const bf16_8*>(
            Qh + (size_t)(q0 + (lane & 15)) * HDIM + db * 32 + (lane >> 4) * 8);

    f32x4 o[4] = {};
    float mrow[4], lrow[4];
    #pragma unroll
    for (int r = 0; r < 4; r++) { mrow[r] = -__builtin_inff(); lrow[r] = 0.f; }

    const float scale = 0.125f; // 1/sqrt(64)
    const int ntiles = bx * 2 + 2;
    const int srow = tid >> 3;        // 0..31
    const int scol = (tid & 7) << 3;  // 0..56

    for (int t = 0; t < ntiles; t++) {
        const int kv0 = t * 32;
        uint4 kvK = *reinterpret_cast<const uint4*>(Kh + (size_t)(kv0 + srow) * HDIM + scol);
        uint4 kvV = *reinterpret_cast<const uint4*>(Vh + (size_t)(kv0 + srow) * HDIM + scol);
        __syncthreads();
        *reinterpret_cast<uint4*>(&Ks[srow][scol]) = kvK;
        *reinterpret_cast<uint4*>(&Vs[srow][scol]) = kvV;
        __syncthreads();

        // scores: 16 q-rows x 32 kj
        f32x4 sc[2] = {};
        #pragma unroll
        for (int nt = 0; nt < 2; nt++) {
            #pragma unroll
            for (int db = 0; db < 2; db++) {
                bf16_8 kf = *reinterpret_cast<const bf16_8*>(
                    &Ks[nt * 16 + (lane & 15)][db * 32 + (lane >> 4) * 8]);
                sc[nt] = __builtin_amdgcn_mfma_f32_16x16x32_bf16(qf[db], kf, sc[nt], 0, 0, 0);
            }
        }
        // scale + causal mask + row max
        float pmax[4];
        #pragma unroll
        for (int r = 0; r < 4; r++) pmax[r] = -__builtin_inff();
        const int qrb = q0 + (lane >> 4) * 4;
        #pragma unroll
        for (int nt = 0; nt < 2; nt++) {
            int kj = kv0 + nt * 16 + (lane & 15);
            #pragma unroll
            for (int r = 0; r < 4; r++) {
                float sv = sc[nt][r] * scale;
                if (kj > qrb + r) sv = -__builtin_inff();
                sc[nt][r] = sv;
                pmax[r] = fmaxf(pmax[r], sv);
            }
        }
        #pragma unroll
        for (int off = 1; off < 16; off <<= 1)
            #pragma unroll
            for (int r = 0; r < 4; r++)
                pmax[r] = fmaxf(pmax[r], __shfl_xor(pmax[r], off, 64));
        float f[4], rs[4];
        #pragma unroll
        for (int r = 0; r < 4; r++) {
            float mn = fmaxf(mrow[r], pmax[r]);
            f[r] = __expf(mrow[r] - mn);
            mrow[r] = mn;
            rs[r] = 0.f;
        }
        // P (bf16) into LDS (D-layout), row sums on rounded values
        #pragma unroll
        for (int nt = 0; nt < 2; nt++) {
            #pragma unroll
            for (int r = 0; r < 4; r++) {
                float p = __expf(sc[nt][r] - mrow[r]);
                u16 pb = f2bf(p);
                Ps[wid][(lane >> 4) * 4 + r][nt * 16 + (lane & 15)] = pb;
                rs[r] += bf2f(pb);
            }
        }
        #pragma unroll
        for (int off = 1; off < 16; off <<= 1)
            #pragma unroll
            for (int r = 0; r < 4; r++)
                rs[r] += __shfl_xor(rs[r], off, 64);
        #pragma unroll
        for (int r = 0; r < 4; r++) lrow[r] = lrow[r] * f[r] + rs[r];
        #pragma unroll
        for (int dt = 0; dt < 4; dt++)
            #pragma unroll
            for (int r = 0; r < 4; r++)
                o[dt][r] *= f[r];

        // PV: P (A-layout from LDS) x V
        asm volatile("" ::: "memory");
        bf16_8 pf = *reinterpret_cast<const bf16_8*>(&Ps[wid][lane & 15][(lane >> 4) * 8]);
        #pragma unroll
        for (int dt = 0; dt < 4; dt++) {
            union { u16 u[8]; bf16_8 b; } vv;
            #pragma unroll
            for (int j = 0; j < 8; j++)
                vv.u[j] = Vs[(lane >> 4) * 8 + j][dt * 16 + (lane & 15)];
            o[dt] = __builtin_amdgcn_mfma_f32_16x16x32_bf16(pf, vv.b, o[dt], 0, 0, 0);
        }
    }
    // epilogue: normalize and store (S, D) bf16
    #pragma unroll
    for (int dt = 0; dt < 4; dt++) {
        #pragma unroll
        for (int r = 0; r < 4; r++) {
            int qi = q0 + (lane >> 4) * 4 + r;
            int d = dt * 16 + (lane & 15);
            float val = o[dt][r] / lrow[r];
            AO[(size_t)qi * DMODEL + h * HDIM + d] = f2bf(val);
        }
    }
}

extern "C" void kernel_launch(void* const* d_in, const int* in_sizes, int n_in,
                              void* d_out, int out_size, void* d_ws, size_t ws_size,
                              hipStream_t stream) {
    const float* x  = (const float*)d_in[0];
    const float* Wq = (const float*)d_in[1];
    const float* bq = (const float*)d_in[2];
    const float* Wk = (const float*)d_in[3];
    const float* bk = (const float*)d_in[4];
    const float* Wv = (const float*)d_in[5];
    const float* bv = (const float*)d_in[6];
    const float* Wo = (const float*)d_in[7];
    const float* bo = (const float*)d_in[8];
    float* out = (float*)d_out;

    const size_t SZ_X = (size_t)S_LEN * DMODEL;   // 4M elements
    const size_t SZ_W = (size_t)DMODEL * DMODEL;  // 1M elements

    char* ws = (char*)d_ws;
    u16* xb  = (u16*)ws;                ws += SZ_X * 2;
    u16* Wqb = (u16*)ws;                ws += SZ_W * 2;
    u16* Wkb = (u16*)ws;                ws += SZ_W * 2;
    u16* Wvb = (u16*)ws;                ws += SZ_W * 2;
    u16* Wob = (u16*)ws;                ws += SZ_W * 2;
    u16* Qb  = (u16*)ws;                ws += SZ_X * 2;
    u16* Kb  = (u16*)ws;                ws += SZ_X * 2;
    u16* Vb  = (u16*)ws;                ws += SZ_X * 2;
    u16* AO  = (u16*)ws;                ws += SZ_X * 2;
    float* cosT = (float*)ws;           ws += (size_t)S_LEN * 32 * 4;
    float* sinT = (float*)ws;

    cvt_kernel<<<dim3(2048), dim3(256), 0, stream>>>(x,  xb,  (int)SZ_X);
    cvt_kernel<<<dim3(1024), dim3(256), 0, stream>>>(Wq, Wqb, (int)SZ_W);
    cvt_kernel<<<dim3(1024), dim3(256), 0, stream>>>(Wk, Wkb, (int)SZ_W);
    cvt_kernel<<<dim3(1024), dim3(256), 0, stream>>>(Wv, Wvb, (int)SZ_W);
    cvt_kernel<<<dim3(1024), dim3(256), 0, stream>>>(Wo, Wob, (int)SZ_W);
    rope_table_kernel<<<dim3((S_LEN * 32) / 256), dim3(256), 0, stream>>>(cosT, sinT);

    gemm_bt_kernel<0><<<dim3(DMODEL / 64, S_LEN / 64, 3), dim3(256), 0, stream>>>(
        xb, Wqb, Wkb, Wvb, bq, bk, bv, Qb, Kb, Vb, nullptr);

    rope_kernel<<<dim3((NHEADS * S_LEN * 32) / 256, 2), dim3(256), 0, stream>>>(Qb, Kb, cosT, sinT);

    attn_kernel<<<dim3(S_LEN / 64, NHEADS), dim3(256), 0, stream>>>(Qb, Kb, Vb, AO);

    gemm_bt_kernel<1><<<dim3(DMODEL / 64, S_LEN / 64, 1), dim3(256), 0, stream>>>(
        AO, Wob, Wob, Wob, bo, bo, bo, nullptr, nullptr, nullptr, out);
}

// Round 6
// 439.647 us; speedup vs baseline: 1.4363x; 1.4363x over previous
//
#include <hip/hip_runtime.h>
#include <hip/hip_bf16.h>

#define S_LEN 4096
#define DMODEL 1024
#define NHEADS 16
#define HDIM 64

typedef __bf16 bf16_8 __attribute__((ext_vector_type(8)));
typedef float f32x4 __attribute__((ext_vector_type(4)));
typedef unsigned short u16;
typedef unsigned int u32;

__device__ __forceinline__ u16 f2bf(float f) {
    union { float f; u32 u; } v; v.f = f;
    u32 r = v.u + 0x7FFFu + ((v.u >> 16) & 1u);
    return (u16)(r >> 16);
}
__device__ __forceinline__ float bf2f(u16 h) {
    union { u32 u; float f; } v; v.u = ((u32)h) << 16;
    return v.f;
}

// async global->LDS, 16B per lane; dest = wave-uniform base + lane*16
__device__ __forceinline__ void gld16(const u16* g, u16* l) {
    __builtin_amdgcn_global_load_lds(
        (const __attribute__((address_space(1))) u32*)g,
        (__attribute__((address_space(3))) u32*)l, 16, 0, 0);
}

// ---------------- fp32 -> bf16 conversion ----------------
__global__ void cvt_kernel(const float* __restrict__ src, u16* __restrict__ dst, int n) {
    int i = (blockIdx.x * blockDim.x + threadIdx.x) * 4;
    int stride = gridDim.x * blockDim.x * 4;
    for (; i < n; i += stride) {
        float4 v = *reinterpret_cast<const float4*>(src + i);
        ushort4 o;
        o.x = f2bf(v.x); o.y = f2bf(v.y); o.z = f2bf(v.z); o.w = f2bf(v.w);
        *reinterpret_cast<ushort4*>(dst + i) = o;
    }
}

// ---------------- RoPE tables ----------------
__global__ void rope_table_kernel(float* __restrict__ cosT, float* __restrict__ sinT) {
    int idx = blockIdx.x * blockDim.x + threadIdx.x;
    if (idx >= S_LEN * 32) return;
    int s = idx >> 5, i = idx & 31;
    float inv = expf(-((float)(2 * i) / (float)HDIM) * logf(10000.0f));
    float fr = (float)s * inv;
    cosT[idx] = cosf(fr);
    sinT[idx] = sinf(fr);
}

// ---------------- GEMM: C = A(MxK) @ B(NxK)^T + bias  (m97 structure) ----------------
// BM=BN=128, BK=32, 256 thr (4 waves 2x2), per-wave 64x64 = acc[4][4]
// MODE 0: three outputs (Q,K,V) by blockIdx.z, bf16 (H,S,hd), RoPE fused for z<2
// MODE 1: single fp32 output (S,D) + bias
template<int MODE>
__global__ __launch_bounds__(256) void gemm_kernel(
    const u16* __restrict__ A,
    const u16* __restrict__ B0, const u16* __restrict__ B1, const u16* __restrict__ B2,
    const float* __restrict__ bias0, const float* __restrict__ bias1, const float* __restrict__ bias2,
    u16* __restrict__ dst0, u16* __restrict__ dst1, u16* __restrict__ dst2,
    float* __restrict__ outF,
    const float* __restrict__ cosT, const float* __restrict__ sinT)
{
    const int bm = blockIdx.y * 128;
    const int bn = blockIdx.x * 128;
    const u16* B = B0; const float* bias = bias0; u16* dst = dst0;
    bool rope = (MODE == 0);
    if (MODE == 0) {
        if (blockIdx.z == 1)      { B = B1; bias = bias1; dst = dst1; }
        else if (blockIdx.z == 2) { B = B2; bias = bias2; dst = dst2; rope = false; }
    }
    __shared__ __align__(16) u16 As[128 * 32];
    __shared__ __align__(16) u16 Bs[128 * 32];
    const int tid = threadIdx.x, lane = tid & 63, wid = tid >> 6;
    const int wm = (wid >> 1) * 64, wn = (wid & 1) * 64;
    // staging: linear row-major [128][32]
    const int srow = wid * 16 + (lane >> 2);
    const int scol = (lane & 3) * 8;
    const size_t aoff = (size_t)(bm + srow) * DMODEL + scol;
    const size_t boff = (size_t)(bn + srow) * DMODEL + scol;
    u16* lA = As + wid * 512;
    u16* lB = Bs + wid * 512;

    f32x4 acc[4][4] = {};
    for (int k0 = 0; k0 < DMODEL; k0 += 32) {
        __syncthreads();
        gld16(A + aoff + k0, lA);
        gld16(A + aoff + (size_t)64 * DMODEL + k0, lA + 2048);
        gld16(B + boff + k0, lB);
        gld16(B + boff + (size_t)64 * DMODEL + k0, lB + 2048);
        __syncthreads();
        bf16_8 af[4], bf[4];
        #pragma unroll
        for (int i = 0; i < 4; i++) {
            af[i] = *(const bf16_8*)&As[(wm + i * 16 + (lane & 15)) * 32 + (lane >> 4) * 8];
            bf[i] = *(const bf16_8*)&Bs[(wn + i * 16 + (lane & 15)) * 32 + (lane >> 4) * 8];
        }
        #pragma unroll
        for (int i = 0; i < 4; i++)
            #pragma unroll
            for (int j = 0; j < 4; j++)
                acc[i][j] = __builtin_amdgcn_mfma_f32_16x16x32_bf16(af[i], bf[j], acc[i][j], 0, 0, 0);
    }

    #pragma unroll
    for (int mi = 0; mi < 4; mi++) {
        #pragma unroll
        for (int ni = 0; ni < 2; ni++) {
            const int d1 = ni * 16 + (lane & 15);
            const int col1 = bn + wn + d1;
            const float b1 = bias[col1], b2 = bias[col1 + 32];
            #pragma unroll
            for (int r = 0; r < 4; r++) {
                const int row = bm + wm + mi * 16 + (lane >> 4) * 4 + r;
                float x1 = acc[mi][ni][r] + b1;
                float x2 = acc[mi][ni + 2][r] + b2;
                if (MODE == 0) {
                    float y1 = x1, y2 = x2;
                    if (rope) {
                        float c = cosT[(row << 5) + d1], s = sinT[(row << 5) + d1];
                        y1 = x1 * c - x2 * s;
                        y2 = x2 * c + x1 * s;
                    }
                    const int h = (bn + wn) >> 6;
                    dst[((size_t)h * S_LEN + row) * HDIM + d1]      = f2bf(y1);
                    dst[((size_t)h * S_LEN + row) * HDIM + d1 + 32] = f2bf(y2);
                } else {
                    outF[(size_t)row * DMODEL + col1]      = x1;
                    outF[(size_t)row * DMODEL + col1 + 32] = x2;
                }
            }
        }
    }
}

// ---------------- causal flash attention ----------------
// grid (S/128, H) with bx reversed (big blocks first); 4 waves, wave w owns q-rows [q0, q0+32)
// K in LDS: linear-swizzled, slot = (d>>3)^(kv&7), staged via global_load_lds w/ pre-swizzled src
// V in LDS: transposed Vt[d][kv], slot = (kv>>3)^(d&7), reg-staged with lane-staggered writes
// Ps stride 72 u16 = 144 B: 16B-aligned row base (REQUIRED for bf16_8 ds_read_b128)
__global__ __launch_bounds__(256) void attn_kernel(
    const u16* __restrict__ Q, const u16* __restrict__ K, const u16* __restrict__ V,
    u16* __restrict__ AO)
{
    const int bxr = (int)(gridDim.x - 1 - blockIdx.x);
    const int h = blockIdx.y;
    const int tid = threadIdx.x, lane = tid & 63, wid = tid >> 6;
    const int q0 = bxr * 128 + wid * 32;
    const u16* Qh = Q + (size_t)h * S_LEN * HDIM;
    const u16* Kh = K + (size_t)h * S_LEN * HDIM;
    const u16* Vh = V + (size_t)h * S_LEN * HDIM;

    __shared__ __align__(16) u16 Ks[64 * 64];
    __shared__ __align__(16) u16 Vt[64 * 64];
    __shared__ __align__(16) u16 Ps[4][32][72];

    // Q fragments, pre-scaled by 1/sqrt(64)=0.125 (exact in bf16)
    bf16_8 qf[2][2];
    #pragma unroll
    for (int m = 0; m < 2; m++)
        #pragma unroll
        for (int db = 0; db < 2; db++) {
            const u16* qp = Qh + (size_t)(q0 + m * 16 + (lane & 15)) * HDIM + db * 32 + (lane >> 4) * 8;
            union { uint4 q; u16 u[8]; } t; t.q = *(const uint4*)qp;
            union { u16 u[8]; bf16_8 b; } ob;
            #pragma unroll
            for (int j = 0; j < 8; j++) ob.u[j] = f2bf(bf2f(t.u[j]) * 0.125f);
            qf[m][db] = ob.b;
        }

    // K staging per-lane fixed offsets
    const int kvl0 = wid * 8 + (lane >> 3);
    const int koff0 = kvl0 * 64 + (((lane & 7) ^ (kvl0 & 7)) << 3);
    const int kvl1 = kvl0 + 32;
    const int koff1 = kvl1 * 64 + (((lane & 7) ^ (kvl1 & 7)) << 3);
    u16* lK0 = Ks + wid * 512;
    u16* lK1 = Ks + 2048 + wid * 512;
    // V staging
    const int vkv0 = tid >> 3;        // 0..31
    const int vd0 = (tid & 7) * 8;
    const int vst = tid & 7;

    f32x4 o[2][4] = {};
    float mrow[2][4], lrow[2][4];
    #pragma unroll
    for (int m = 0; m < 2; m++)
        #pragma unroll
        for (int r = 0; r < 4; r++) { mrow[m][r] = -__builtin_inff(); lrow[m][r] = 0.f; }

    union { u16 u[8]; bf16_8 b; } onesu;
    #pragma unroll
    for (int j = 0; j < 8; j++) onesu.u[j] = 0x3F80;
    const bf16_8 ones = onesu.b;

    const int ntiles = bxr * 2 + 2;
    const int ndiag = ntiles - 2;

    for (int t = 0; t < ntiles; t++) {
        const u16* Kg = Kh + (size_t)t * 4096;
        const u16* Vg = Vh + (size_t)t * 4096;
        union { uint4 q; u16 u[8]; } va, vb;
        va.q = *(const uint4*)(Vg + tid * 8);
        vb.q = *(const uint4*)(Vg + 2048 + tid * 8);
        __syncthreads();
        gld16(Kg + koff0, lK0);
        gld16(Kg + koff1, lK1);
        #pragma unroll
        for (int jj = 0; jj < 8; jj++) {
            const int j = (jj + vst) & 7;
            Vt[(vd0 + j) * 64 + (((vkv0 >> 3) ^ j) << 3) + (vkv0 & 7)] = va.u[j];
            Vt[(vd0 + j) * 64 + ((((vkv0 + 32) >> 3) ^ j) << 3) + (vkv0 & 7)] = vb.u[j];
        }
        __syncthreads();

        // QK^T: sc[m][nt] over 32 q-rows x 64 kv
        f32x4 sc[2][4];
        #pragma unroll
        for (int m = 0; m < 2; m++)
            #pragma unroll
            for (int nt = 0; nt < 4; nt++) sc[m][nt] = (f32x4){0.f, 0.f, 0.f, 0.f};
        #pragma unroll
        for (int nt = 0; nt < 4; nt++) {
            const int kvr = nt * 16 + (lane & 15);
            #pragma unroll
            for (int db = 0; db < 2; db++) {
                bf16_8 kf = *(const bf16_8*)&Ks[kvr * 64 + (((db * 4 + (lane >> 4)) ^ (lane & 7)) << 3)];
                sc[0][nt] = __builtin_amdgcn_mfma_f32_16x16x32_bf16(qf[0][db], kf, sc[0][nt], 0, 0, 0);
                sc[1][nt] = __builtin_amdgcn_mfma_f32_16x16x32_bf16(qf[1][db], kf, sc[1][nt], 0, 0, 0);
            }
        }
        // causal mask: only the two diagonal tiles
        if (t >= ndiag) {
            #pragma unroll
            for (int m = 0; m < 2; m++)
                #pragma unroll
                for (int nt = 0; nt < 4; nt++) {
                    const int kj = t * 64 + nt * 16 + (lane & 15);
                    #pragma unroll
                    for (int r = 0; r < 4; r++) {
                        const int qi = q0 + m * 16 + (lane >> 4) * 4 + r;
                        if (kj > qi) sc[m][nt][r] = -1e30f;
                    }
                }
        }
        // row max (reduce over nt then over lane&15)
        float pmax[2][4], fs[2][4];
        #pragma unroll
        for (int m = 0; m < 2; m++)
            #pragma unroll
            for (int r = 0; r < 4; r++)
                pmax[m][r] = fmaxf(fmaxf(sc[m][0][r], sc[m][1][r]), fmaxf(sc[m][2][r], sc[m][3][r]));
        #pragma unroll
        for (int off = 1; off < 16; off <<= 1)
            #pragma unroll
            for (int m = 0; m < 2; m++)
                #pragma unroll
                for (int r = 0; r < 4; r++)
                    pmax[m][r] = fmaxf(pmax[m][r], __shfl_xor(pmax[m][r], off, 64));
        #pragma unroll
        for (int m = 0; m < 2; m++)
            #pragma unroll
            for (int r = 0; r < 4; r++) {
                const float mn = fmaxf(mrow[m][r], pmax[m][r]);
                fs[m][r] = __expf(mrow[m][r] - mn);
                mrow[m][r] = mn;
            }
        // P -> LDS (bf16), and rescale o
        #pragma unroll
        for (int m = 0; m < 2; m++)
            #pragma unroll
            for (int nt = 0; nt < 4; nt++)
                #pragma unroll
                for (int r = 0; r < 4; r++) {
                    const float p = __expf(sc[m][nt][r] - mrow[m][r]);
                    Ps[wid][m * 16 + (lane >> 4) * 4 + r][nt * 16 + (lane & 15)] = f2bf(p);
                }
        #pragma unroll
        for (int m = 0; m < 2; m++)
            #pragma unroll
            for (int dt = 0; dt < 4; dt++)
                #pragma unroll
                for (int r = 0; r < 4; r++) o[m][dt][r] *= fs[m][r];
        asm volatile("" ::: "memory");
        // PV + rowsum-via-MFMA(ones)
        f32x4 ls[2] = {};
        #pragma unroll
        for (int ks = 0; ks < 2; ks++) {
            bf16_8 pa[2];
            #pragma unroll
            for (int m = 0; m < 2; m++)
                pa[m] = *(const bf16_8*)&Ps[wid][m * 16 + (lane & 15)][ks * 32 + (lane >> 4) * 8];
            ls[0] = __builtin_amdgcn_mfma_f32_16x16x32_bf16(pa[0], ones, ls[0], 0, 0, 0);
            ls[1] = __builtin_amdgcn_mfma_f32_16x16x32_bf16(pa[1], ones, ls[1], 0, 0, 0);
            #pragma unroll
            for (int dt = 0; dt < 4; dt++) {
                const int d = dt * 16 + (lane & 15);
                bf16_8 vf = *(const bf16_8*)&Vt[d * 64 + (((ks * 4 + (lane >> 4)) ^ (lane & 7)) << 3)];
                o[0][dt] = __builtin_amdgcn_mfma_f32_16x16x32_bf16(pa[0], vf, o[0][dt], 0, 0, 0);
                o[1][dt] = __builtin_amdgcn_mfma_f32_16x16x32_bf16(pa[1], vf, o[1][dt], 0, 0, 0);
            }
        }
        #pragma unroll
        for (int m = 0; m < 2; m++)
            #pragma unroll
            for (int r = 0; r < 4; r++)
                lrow[m][r] = lrow[m][r] * fs[m][r] + ls[m][r];
    }
    // epilogue: normalize, store (S, D) bf16
    #pragma unroll
    for (int m = 0; m < 2; m++)
        #pragma unroll
        for (int dt = 0; dt < 4; dt++)
            #pragma unroll
            for (int r = 0; r < 4; r++) {
                const int qi = q0 + m * 16 + (lane >> 4) * 4 + r;
                const int d = dt * 16 + (lane & 15);
                AO[(size_t)qi * DMODEL + h * HDIM + d] = f2bf(o[m][dt][r] / lrow[m][r]);
            }
}

extern "C" void kernel_launch(void* const* d_in, const int* in_sizes, int n_in,
                              void* d_out, int out_size, void* d_ws, size_t ws_size,
                              hipStream_t stream) {
    const float* x  = (const float*)d_in[0];
    const float* Wq = (const float*)d_in[1];
    const float* bq = (const float*)d_in[2];
    const float* Wk = (const float*)d_in[3];
    const float* bk = (const float*)d_in[4];
    const float* Wv = (const float*)d_in[5];
    const float* bv = (const float*)d_in[6];
    const float* Wo = (const float*)d_in[7];
    const float* bo = (const float*)d_in[8];
    float* out = (float*)d_out;

    const size_t SZ_X = (size_t)S_LEN * DMODEL;   // 4M elements
    const size_t SZ_W = (size_t)DMODEL * DMODEL;  // 1M elements

    char* ws = (char*)d_ws;
    u16* xb  = (u16*)ws;                ws += SZ_X * 2;
    u16* Wqb = (u16*)ws;                ws += SZ_W * 2;
    u16* Wkb = (u16*)ws;                ws += SZ_W * 2;
    u16* Wvb = (u16*)ws;                ws += SZ_W * 2;
    u16* Wob = (u16*)ws;                ws += SZ_W * 2;
    u16* Qb  = (u16*)ws;                ws += SZ_X * 2;
    u16* Kb  = (u16*)ws;                ws += SZ_X * 2;
    u16* Vb  = (u16*)ws;                ws += SZ_X * 2;
    u16* AO  = (u16*)ws;                ws += SZ_X * 2;
    float* cosT = (float*)ws;           ws += (size_t)S_LEN * 32 * 4;
    float* sinT = (float*)ws;

    cvt_kernel<<<dim3(2048), dim3(256), 0, stream>>>(x,  xb,  (int)SZ_X);
    cvt_kernel<<<dim3(1024), dim3(256), 0, stream>>>(Wq, Wqb, (int)SZ_W);
    cvt_kernel<<<dim3(1024), dim3(256), 0, stream>>>(Wk, Wkb, (int)SZ_W);
    cvt_kernel<<<dim3(1024), dim3(256), 0, stream>>>(Wv, Wvb, (int)SZ_W);
    cvt_kernel<<<dim3(1024), dim3(256), 0, stream>>>(Wo, Wob, (int)SZ_W);
    rope_table_kernel<<<dim3((S_LEN * 32) / 256), dim3(256), 0, stream>>>(cosT, sinT);

    gemm_kernel<0><<<dim3(DMODEL / 128, S_LEN / 128, 3), dim3(256), 0, stream>>>(
        xb, Wqb, Wkb, Wvb, bq, bk, bv, Qb, Kb, Vb, nullptr, cosT, sinT);

    attn_kernel<<<dim3(S_LEN / 128, NHEADS), dim3(256), 0, stream>>>(Qb, Kb, Vb, AO);

    gemm_kernel<1><<<dim3(DMODEL / 128, S_LEN / 128, 1), dim3(256), 0, stream>>>(
        AO, Wob, Wob, Wob, bo, bo, bo, nullptr, nullptr, nullptr, out, cosT, sinT);
}